// Round 6
// baseline (298.938 us; speedup 1.0000x reference)
//
#include <hip/hip_runtime.h>

// B=4, N=8, C=256, H=64, W=64, D=512 (single query per batch).
// Algebraic collapse: c is read exactly once; K and V never formed.
//   gqk[b,c]  = g[c] * D^-0.5 * (Wkv_upper^T (Wq q_b))[c]
//   dots[n]   = inv_rms[n,px] * <c[b,n,:,px], gqk[b,:]>
//   t[c,px]   = sum_n softmax_n * inv_rms * c[b,n,c,px]
//   out       = Wovg @ t + bo,  Wovg = Wo @ Wkv_lower * diag(g)  (bf16 MFMA)
//
// R8: spans (128B..4KB) falsified as the lever (R7==R2); evidence points at
// memory-level parallelism + per-token latency serialization (17.5K cy/token
// vs ~2K accounted; R4's high-occupancy passes ran ~3 TB/s vs R7's 2.5).
// So: split tokens across blocks (n-halves) with online-softmax merge.
//   attn: 1024 blocks x 256 thr, thread = 8ch x 4px (~100 VGPR, cap 128,
//         4 blocks/CU = 16 waves/CU, 2x R7) and 4 serial rounds (1/2 R7).
//         Writes unnormalized te (bf16 fragments) + (m,Z) per px per half.
//   gemm: merges halves in B-staging: B = f1*te1 + f2*te2, f from (m,Z).
// ws: [0,131072)          WovgB bf16 A-fragment-linear:
//                         (i,c) -> ((((i>>4)*8+(c>>5))*4+((c>>3)&3))*16+(i&15))*8+(c&7)
//     [131072,135168)     gqk f32 [4][256]
//     [135168,397312)     mz float2 [2 half][4 b][4096 px] = (m, Z)
//     [397312,8785920)    te half 0: short8[((b*256+P)*8+s)*4+q)*16+m]
//     [8785920,17174528)  te half 1: same layout

typedef __attribute__((ext_vector_type(8))) short short8;
typedef __attribute__((ext_vector_type(4))) float floatx4;

static __device__ __forceinline__ short f2bf(float f) {
  unsigned u = __float_as_uint(f);
  u += 0x7fffu + ((u >> 16) & 1u);   // round-to-nearest-even
  return (short)(u >> 16);
}
static __device__ __forceinline__ float bf2f(short s) {
  return __uint_as_float(((unsigned)(unsigned short)s) << 16);
}

// blocks 0..63: Wovg rows 4i..4i+3; blocks 64..67: gqk for batch b
__global__ __launch_bounds__(256) void pre_kernel(
    const float* __restrict__ q, const float* __restrict__ g,
    const float* __restrict__ Wq, const float* __restrict__ Wkv,
    const float* __restrict__ Wo, unsigned char* __restrict__ ws) {
  short* WovgB = (short*)ws;
  float* gqk = (float*)(ws + 131072);
  const int blk = blockIdx.x, tid = threadIdx.x;
  if (blk < 64) {
    const int i0 = blk * 4, c = tid;
    float s0 = 0.f, s1 = 0.f, s2 = 0.f, s3 = 0.f;
    #pragma unroll 8
    for (int d = 0; d < 512; ++d) {
      const float wv = Wkv[(512 + d) * 256 + c];   // vector load
      s0 = fmaf(Wo[(i0 + 0) * 512 + d], wv, s0);   // Wo: uniform -> s_load
      s1 = fmaf(Wo[(i0 + 1) * 512 + d], wv, s1);
      s2 = fmaf(Wo[(i0 + 2) * 512 + d], wv, s2);
      s3 = fmaf(Wo[(i0 + 3) * 512 + d], wv, s3);
    }
    const float gc = g[c];
    const int sg = c >> 5, q2 = (c >> 3) & 3, jj = c & 7;
    const float sv[4] = {s0, s1, s2, s3};
    #pragma unroll
    for (int ii = 0; ii < 4; ++ii) {
      const int i = i0 + ii, it = i >> 4, m = i & 15;
      WovgB[((((it * 8 + sg) * 4 + q2) * 16) + m) * 8 + jj] = f2bf(sv[ii] * gc);
    }
  } else if (blk < 68) {
    const int b = blk - 64;
    __shared__ float qps[512];
    for (int d = tid; d < 512; d += 256) {
      float s = 0.f;
      #pragma unroll 16
      for (int cc = 0; cc < 256; ++cc)
        s = fmaf(Wq[d * 256 + cc], q[b * 256 + cc], s);
      qps[d] = s;
    }
    __syncthreads();
    const int c = tid;
    float s = 0.f;
    #pragma unroll 16
    for (int d = 0; d < 512; ++d)
      s = fmaf(Wkv[d * 256 + c], qps[d], s);
    gqk[b * 256 + c] = s * g[c] * 0.044194173824159216f;  // 512^-0.5
  }
}

// Block = (b, h_row, hf, nh): 32 px, 4 tokens. 1024 blocks x 256 thr.
// Thread: co = tid>>3 owns ch [co*8, co*8+8); pg = tid&7 owns px pg*4..+4.
__global__ __launch_bounds__(256, 4) void attn_kernel(
    const float* __restrict__ cin, const unsigned char* __restrict__ wsc,
    unsigned char* __restrict__ ws) {
  const float* gqk = (const float*)(wsc + 131072);
  float2* mz = (float2*)(ws + 135168);
  const int blk = blockIdx.x;
  const int b = blk >> 8, h = (blk >> 2) & 63, hf = (blk >> 1) & 1, nh = blk & 1;
  const int tid = threadIdx.x;
  const int lane = tid & 63, w = tid >> 6;    // w in 0..3
  const int co = tid >> 3, pg = tid & 7;      // co 0..31, pg 0..7

  __shared__ float redS[2][4][8][4], redD[2][4][8][4];   // 2 KB

  float rg[8];
  #pragma unroll
  for (int j = 0; j < 8; ++j) rg[j] = gqk[b * 256 + co * 8 + j];

  float t[8][4];
  #pragma unroll
  for (int j = 0; j < 8; ++j)
    #pragma unroll
    for (int p = 0; p < 4; ++p) t[j][p] = 0.f;
  float mM[4], zZ[4];
  #pragma unroll
  for (int p = 0; p < 4; ++p) { mM[p] = -1e30f; zZ[p] = 0.f; }

  const float* cb = cin + ((size_t)((b * 8 + nh * 4) * 256) + co * 8) * 4096
                        + h * 64 + hf * 32 + pg * 4;
  for (int n = 0; n < 4; ++n) {
    const float* cp = cb + (size_t)n * 256 * 4096;
    floatx4 vals[8];
    #pragma unroll
    for (int j = 0; j < 8; ++j)
      vals[j] = *(const floatx4*)(cp + (size_t)j * 4096);
    float ssq[4] = {0.f, 0.f, 0.f, 0.f}, dt[4] = {0.f, 0.f, 0.f, 0.f};
    #pragma unroll
    for (int j = 0; j < 8; ++j)
      #pragma unroll
      for (int p = 0; p < 4; ++p) {
        ssq[p] = fmaf(vals[j][p], vals[j][p], ssq[p]);
        dt[p] = fmaf(vals[j][p], rg[j], dt[p]);
      }
    // sum over the wave's 8 co-octets (lane bits 3,4,5); pg preserved
    #pragma unroll
    for (int p = 0; p < 4; ++p) {
      ssq[p] += __shfl_xor(ssq[p], 8);
      ssq[p] += __shfl_xor(ssq[p], 16);
      ssq[p] += __shfl_xor(ssq[p], 32);
      dt[p] += __shfl_xor(dt[p], 8);
      dt[p] += __shfl_xor(dt[p], 16);
      dt[p] += __shfl_xor(dt[p], 32);
    }
    if (lane < 8) {
      #pragma unroll
      for (int p = 0; p < 4; ++p) {
        redS[n & 1][w][pg][p] = ssq[p];
        redD[n & 1][w][pg][p] = dt[p];
      }
    }
    __syncthreads();                          // the only barrier per token
    floatx4 S = {0.f, 0.f, 0.f, 0.f}, Dt = {0.f, 0.f, 0.f, 0.f};
    #pragma unroll
    for (int ww = 0; ww < 4; ++ww) {
      S += *(const floatx4*)(&redS[n & 1][ww][pg][0]);
      Dt += *(const floatx4*)(&redD[n & 1][ww][pg][0]);
    }
    float wn[4], al[4];
    #pragma unroll
    for (int p = 0; p < 4; ++p) {
      const float invr = rsqrtf(S[p] * (1.f / 256.f) + 1e-6f);
      const float d = Dt[p] * invr;
      const float mn = fmaxf(mM[p], d);
      al[p] = __expf(mM[p] - mn);             // 0 on first token
      const float e = __expf(d - mn);
      zZ[p] = zZ[p] * al[p] + e;
      mM[p] = mn;
      wn[p] = e * invr;
    }
    #pragma unroll
    for (int j = 0; j < 8; ++j)
      #pragma unroll
      for (int p = 0; p < 4; ++p)
        t[j][p] = fmaf(wn[p], vals[j][p], t[j][p] * al[p]);
  }

  // write UNNORMALIZED te fragments (bf16): ch = co*8+j -> s=co>>2, q=co&3,
  // jj=j; px = h*64+hf*32+pg*4+p -> P = h*4+hf*2+(pg>>2), m = (pg&3)*4+p.
  {
    short8* te = (short8*)(ws + 397312 + (size_t)nh * 8388608);
    const int s = co >> 2, qq = co & 3;
    const int P = h * 4 + hf * 2 + (pg >> 2), mb = (pg & 3) * 4;
    #pragma unroll
    for (int p = 0; p < 4; ++p) {
      short8 pk;
      #pragma unroll
      for (int j = 0; j < 8; ++j) pk[j] = f2bf(t[j][p]);
      te[(((b * 256 + P) * 8 + s) * 4 + qq) * 16 + mb + p] = pk;
    }
  }
  if (tid < 8) {                              // co==0 threads own (m,Z)
    const int px = h * 64 + hf * 32 + pg * 4;
    #pragma unroll
    for (int p = 0; p < 4; ++p)
      mz[((size_t)(nh * 4 + b)) * 4096 + px + p] = make_float2(mM[p], zZ[p]);
  }
}

// gemm: out[64 i][256 px] per block = Wovg(bf16) @ merge(te1,te2) + bo.
// Block = (b, ig, pxg). 256 blocks x 256 thr (4 waves).
__global__ __launch_bounds__(256, 2) void gemm_kernel(
    const float* __restrict__ bo, const unsigned char* __restrict__ ws,
    float* __restrict__ out) {
  const short8* Av = (const short8*)ws;
  const float2* mz = (const float2*)(ws + 135168);
  const short8* T1 = (const short8*)(ws + 397312);
  const short8* T2 = (const short8*)(ws + 8785920);
  __shared__ short8 tBs[1024];   // 16 KB: merged t[32 ch][256 px] for current s
  __shared__ float2 ff[256];     // 2 KB: per-px merge factors (f1, f2)
  const int blk = blockIdx.x, tid = threadIdx.x;
  const int b = blk >> 6, ig = (blk >> 4) & 3, pxg = blk & 15;
  const int lane = tid & 63, w = tid >> 6;
  const int it = ig * 4 + w;                  // wave -> 16 i-rows
  const int qf = lane >> 4, m = lane & 15;

  {                                           // merge factors for this px tile
    const int px = pxg * 256 + tid;
    const float2 a = mz[(size_t)b * 4096 + px];            // half 0 (m,Z)
    const float2 c2 = mz[(size_t)(4 + b) * 4096 + px];     // half 1
    const float M = fmaxf(a.x, c2.x);
    const float s1 = __expf(a.x - M), s2 = __expf(c2.x - M);
    const float den = 1.f / (s1 * a.y + s2 * c2.y);
    ff[tid] = make_float2(s1 * den, s2 * den);
  }
  __syncthreads();

  floatx4 acc[16];
  #pragma unroll
  for (int nt = 0; nt < 16; ++nt) acc[nt] = (floatx4){0.f, 0.f, 0.f, 0.f};
  #pragma unroll
  for (int s = 0; s < 8; ++s) {
    if (s) __syncthreads();                   // protect tBs reuse
    #pragma unroll
    for (int k = 0; k < 4; ++k) {             // stage + merge, 16 B/lane
      const int idx = tid + k * 256;
      const int nt = idx >> 6, r = idx & 63;
      const size_t src = (size_t)((b * 256 + pxg * 16 + nt) * 8 + s) * 64 + r;
      const short8 v1 = T1[src], v2 = T2[src];
      const float2 f = ff[nt * 16 + (r & 15)];
      short8 mg;
      #pragma unroll
      for (int j = 0; j < 8; ++j)
        mg[j] = f2bf(f.x * bf2f(v1[j]) + f.y * bf2f(v2[j]));
      tBs[idx] = mg;
    }
    __syncthreads();
    const short8 a = Av[((it * 8 + s) * 4 + qf) * 16 + m];
    #pragma unroll
    for (int nt = 0; nt < 16; ++nt)
      acc[nt] = __builtin_amdgcn_mfma_f32_16x16x32_bf16(a, tBs[nt * 64 + lane], acc[nt], 0, 0, 0);
  }
  // D layout: col = m (px), row = qf*4 + r (i)
  float* ob = out + (size_t)(b * 256) * 4096 + pxg * 256;
  #pragma unroll
  for (int nt = 0; nt < 16; ++nt)
    #pragma unroll
    for (int r = 0; r < 4; ++r) {
      const int i = it * 16 + qf * 4 + r;
      ob[(size_t)i * 4096 + nt * 16 + m] = acc[nt][r] + bo[i];
    }
}

extern "C" void kernel_launch(void* const* d_in, const int* in_sizes, int n_in,
                              void* d_out, int out_size, void* d_ws, size_t ws_size,
                              hipStream_t stream) {
  const float* q   = (const float*)d_in[0];
  const float* c   = (const float*)d_in[1];
  const float* g   = (const float*)d_in[2];
  const float* Wq  = (const float*)d_in[3];
  const float* Wkv = (const float*)d_in[4];
  const float* Wo  = (const float*)d_in[5];
  const float* bo  = (const float*)d_in[6];
  float* out = (float*)d_out;
  unsigned char* ws = (unsigned char*)d_ws;   // needs 17,174,528 bytes
  pre_kernel<<<68, 256, 0, stream>>>(q, g, Wq, Wkv, Wo, ws);
  attn_kernel<<<1024, 256, 0, stream>>>(c, ws, ws);
  gemm_kernel<<<256, 256, 0, stream>>>(bo, ws, out);
}

// Round 7
// 267.712 us; speedup vs baseline: 1.1166x; 1.1166x over previous
//
#include <hip/hip_runtime.h>

// B=4, N=8, C=256, H=64, W=64, D=512 (single query per batch).
// Algebraic collapse: c is read exactly once; K and V never formed.
//   gqk[b,c]  = g[c] * D^-0.5 * (Wkv_upper^T (Wq q_b))[c]
//   dots[n]   = inv_rms[n,px] * <c[b,n,:,px], gqk[b,:]>
//   t[c,px]   = sum_n softmax_n * inv_rms * c[b,n,c,px]
//   out       = Wovg @ t + bo,  Wovg = Wo @ Wkv_lower * diag(g)  (bf16 MFMA)
//
// R9 = R8 with the spill bug fixed. R8's __launch_bounds__(256,4) made the
// allocator squeeze to 64 VGPR and spill ~100 MB/launch (WRITE_SIZE 117.7 MB
// vs 17 ideal; same failure as R3). Compiler rule observed twice: 2nd arg 4
// -> 64-reg squeeze + spills; 2nd arg 2 -> <=128 VGPR, no spill (R2, R7).
// Structure: tokens split across blocks (n-halves) + online-softmax merge.
//   attn: 1024 blocks x 256 thr (4 blocks/CU -> 16 waves/CU, 2x R7's
//         grid-limited 8), 4 serial token rounds (1/2 R7), thread = 8ch x 4px.
//         Writes unnormalized te (bf16 fragments) + (m,Z) per px per half.
//   gemm: merges halves during B-staging: B = f1*te1 + f2*te2, f from (m,Z).
// ws: [0,131072)          WovgB bf16 A-fragment-linear:
//                         (i,c) -> ((((i>>4)*8+(c>>5))*4+((c>>3)&3))*16+(i&15))*8+(c&7)
//     [131072,135168)     gqk f32 [4][256]
//     [135168,397312)     mz float2 [2 half][4 b][4096 px] = (m, Z)
//     [397312,8785920)    te half 0: short8[((b*256+P)*8+s)*4+q)*16+m]
//     [8785920,17174528)  te half 1: same layout

typedef __attribute__((ext_vector_type(8))) short short8;
typedef __attribute__((ext_vector_type(4))) float floatx4;

static __device__ __forceinline__ short f2bf(float f) {
  unsigned u = __float_as_uint(f);
  u += 0x7fffu + ((u >> 16) & 1u);   // round-to-nearest-even
  return (short)(u >> 16);
}
static __device__ __forceinline__ float bf2f(short s) {
  return __uint_as_float(((unsigned)(unsigned short)s) << 16);
}

// blocks 0..63: Wovg rows 4i..4i+3; blocks 64..67: gqk for batch b
__global__ __launch_bounds__(256) void pre_kernel(
    const float* __restrict__ q, const float* __restrict__ g,
    const float* __restrict__ Wq, const float* __restrict__ Wkv,
    const float* __restrict__ Wo, unsigned char* __restrict__ ws) {
  short* WovgB = (short*)ws;
  float* gqk = (float*)(ws + 131072);
  const int blk = blockIdx.x, tid = threadIdx.x;
  if (blk < 64) {
    const int i0 = blk * 4, c = tid;
    float s0 = 0.f, s1 = 0.f, s2 = 0.f, s3 = 0.f;
    #pragma unroll 8
    for (int d = 0; d < 512; ++d) {
      const float wv = Wkv[(512 + d) * 256 + c];   // vector load
      s0 = fmaf(Wo[(i0 + 0) * 512 + d], wv, s0);   // Wo: uniform -> s_load
      s1 = fmaf(Wo[(i0 + 1) * 512 + d], wv, s1);
      s2 = fmaf(Wo[(i0 + 2) * 512 + d], wv, s2);
      s3 = fmaf(Wo[(i0 + 3) * 512 + d], wv, s3);
    }
    const float gc = g[c];
    const int sg = c >> 5, q2 = (c >> 3) & 3, jj = c & 7;
    const float sv[4] = {s0, s1, s2, s3};
    #pragma unroll
    for (int ii = 0; ii < 4; ++ii) {
      const int i = i0 + ii, it = i >> 4, m = i & 15;
      WovgB[((((it * 8 + sg) * 4 + q2) * 16) + m) * 8 + jj] = f2bf(sv[ii] * gc);
    }
  } else if (blk < 68) {
    const int b = blk - 64;
    __shared__ float qps[512];
    for (int d = tid; d < 512; d += 256) {
      float s = 0.f;
      #pragma unroll 16
      for (int cc = 0; cc < 256; ++cc)
        s = fmaf(Wq[d * 256 + cc], q[b * 256 + cc], s);
      qps[d] = s;
    }
    __syncthreads();
    const int c = tid;
    float s = 0.f;
    #pragma unroll 16
    for (int d = 0; d < 512; ++d)
      s = fmaf(Wkv[d * 256 + c], qps[d], s);
    gqk[b * 256 + c] = s * g[c] * 0.044194173824159216f;  // 512^-0.5
  }
}

// Block = (b, h_row, hf, nh): 32 px, 4 tokens. 1024 blocks x 256 thr.
// Thread: co = tid>>3 owns ch [co*8, co*8+8); pg = tid&7 owns px pg*4..+4.
__global__ __launch_bounds__(256, 2) void attn_kernel(
    const float* __restrict__ cin, const unsigned char* __restrict__ wsc,
    unsigned char* __restrict__ ws) {
  const float* gqk = (const float*)(wsc + 131072);
  float2* mz = (float2*)(ws + 135168);
  const int blk = blockIdx.x;
  const int b = blk >> 8, h = (blk >> 2) & 63, hf = (blk >> 1) & 1, nh = blk & 1;
  const int tid = threadIdx.x;
  const int lane = tid & 63, w = tid >> 6;    // w in 0..3
  const int co = tid >> 3, pg = tid & 7;      // co 0..31, pg 0..7

  __shared__ float redS[2][4][8][4], redD[2][4][8][4];   // 2 KB

  float rg[8];
  #pragma unroll
  for (int j = 0; j < 8; ++j) rg[j] = gqk[b * 256 + co * 8 + j];

  float t[8][4];
  #pragma unroll
  for (int j = 0; j < 8; ++j)
    #pragma unroll
    for (int p = 0; p < 4; ++p) t[j][p] = 0.f;
  float mM[4], zZ[4];
  #pragma unroll
  for (int p = 0; p < 4; ++p) { mM[p] = -1e30f; zZ[p] = 0.f; }

  const float* cb = cin + ((size_t)((b * 8 + nh * 4) * 256) + co * 8) * 4096
                        + h * 64 + hf * 32 + pg * 4;
  for (int n = 0; n < 4; ++n) {
    const float* cp = cb + (size_t)n * 256 * 4096;
    floatx4 vals[8];
    #pragma unroll
    for (int j = 0; j < 8; ++j)
      vals[j] = *(const floatx4*)(cp + (size_t)j * 4096);
    float ssq[4] = {0.f, 0.f, 0.f, 0.f}, dt[4] = {0.f, 0.f, 0.f, 0.f};
    #pragma unroll
    for (int j = 0; j < 8; ++j)
      #pragma unroll
      for (int p = 0; p < 4; ++p) {
        ssq[p] = fmaf(vals[j][p], vals[j][p], ssq[p]);
        dt[p] = fmaf(vals[j][p], rg[j], dt[p]);
      }
    // sum over the wave's 8 co-octets (lane bits 3,4,5); pg preserved
    #pragma unroll
    for (int p = 0; p < 4; ++p) {
      ssq[p] += __shfl_xor(ssq[p], 8);
      ssq[p] += __shfl_xor(ssq[p], 16);
      ssq[p] += __shfl_xor(ssq[p], 32);
      dt[p] += __shfl_xor(dt[p], 8);
      dt[p] += __shfl_xor(dt[p], 16);
      dt[p] += __shfl_xor(dt[p], 32);
    }
    if (lane < 8) {
      #pragma unroll
      for (int p = 0; p < 4; ++p) {
        redS[n & 1][w][pg][p] = ssq[p];
        redD[n & 1][w][pg][p] = dt[p];
      }
    }
    __syncthreads();                          // the only barrier per token
    floatx4 S = {0.f, 0.f, 0.f, 0.f}, Dt = {0.f, 0.f, 0.f, 0.f};
    #pragma unroll
    for (int ww = 0; ww < 4; ++ww) {
      S += *(const floatx4*)(&redS[n & 1][ww][pg][0]);
      Dt += *(const floatx4*)(&redD[n & 1][ww][pg][0]);
    }
    float wn[4], al[4];
    #pragma unroll
    for (int p = 0; p < 4; ++p) {
      const float invr = rsqrtf(S[p] * (1.f / 256.f) + 1e-6f);
      const float d = Dt[p] * invr;
      const float mn = fmaxf(mM[p], d);
      al[p] = __expf(mM[p] - mn);             // 0 on first token
      const float e = __expf(d - mn);
      zZ[p] = zZ[p] * al[p] + e;
      mM[p] = mn;
      wn[p] = e * invr;
    }
    #pragma unroll
    for (int j = 0; j < 8; ++j)
      #pragma unroll
      for (int p = 0; p < 4; ++p)
        t[j][p] = fmaf(wn[p], vals[j][p], t[j][p] * al[p]);
  }

  // write UNNORMALIZED te fragments (bf16): ch = co*8+j -> s=co>>2, q=co&3,
  // jj=j; px = h*64+hf*32+pg*4+p -> P = h*4+hf*2+(pg>>2), m = (pg&3)*4+p.
  {
    short8* te = (short8*)(ws + 397312 + (size_t)nh * 8388608);
    const int s = co >> 2, qq = co & 3;
    const int P = h * 4 + hf * 2 + (pg >> 2), mb = (pg & 3) * 4;
    #pragma unroll
    for (int p = 0; p < 4; ++p) {
      short8 pk;
      #pragma unroll
      for (int j = 0; j < 8; ++j) pk[j] = f2bf(t[j][p]);
      te[(((b * 256 + P) * 8 + s) * 4 + qq) * 16 + mb + p] = pk;
    }
  }
  if (tid < 8) {                              // co==0 threads own (m,Z)
    const int px = h * 64 + hf * 32 + pg * 4;
    #pragma unroll
    for (int p = 0; p < 4; ++p)
      mz[((size_t)(nh * 4 + b)) * 4096 + px + p] = make_float2(mM[p], zZ[p]);
  }
}

// gemm: out[64 i][256 px] per block = Wovg(bf16) @ merge(te1,te2) + bo.
// Block = (b, ig, pxg). 256 blocks x 256 thr (4 waves).
__global__ __launch_bounds__(256, 2) void gemm_kernel(
    const float* __restrict__ bo, const unsigned char* __restrict__ ws,
    float* __restrict__ out) {
  const short8* Av = (const short8*)ws;
  const float2* mz = (const float2*)(ws + 135168);
  const short8* T1 = (const short8*)(ws + 397312);
  const short8* T2 = (const short8*)(ws + 8785920);
  __shared__ short8 tBs[1024];   // 16 KB: merged t[32 ch][256 px] for current s
  __shared__ float2 ff[256];     // 2 KB: per-px merge factors (f1, f2)
  const int blk = blockIdx.x, tid = threadIdx.x;
  const int b = blk >> 6, ig = (blk >> 4) & 3, pxg = blk & 15;
  const int lane = tid & 63, w = tid >> 6;
  const int it = ig * 4 + w;                  // wave -> 16 i-rows
  const int qf = lane >> 4, m = lane & 15;

  {                                           // merge factors for this px tile
    const int px = pxg * 256 + tid;
    const float2 a = mz[(size_t)b * 4096 + px];            // half 0 (m,Z)
    const float2 c2 = mz[(size_t)(4 + b) * 4096 + px];     // half 1
    const float M = fmaxf(a.x, c2.x);
    const float s1 = __expf(a.x - M), s2 = __expf(c2.x - M);
    const float den = 1.f / (s1 * a.y + s2 * c2.y);
    ff[tid] = make_float2(s1 * den, s2 * den);
  }
  __syncthreads();

  floatx4 acc[16];
  #pragma unroll
  for (int nt = 0; nt < 16; ++nt) acc[nt] = (floatx4){0.f, 0.f, 0.f, 0.f};
  #pragma unroll
  for (int s = 0; s < 8; ++s) {
    if (s) __syncthreads();                   // protect tBs reuse
    #pragma unroll
    for (int k = 0; k < 4; ++k) {             // stage + merge, 16 B/lane
      const int idx = tid + k * 256;
      const int nt = idx >> 6, r = idx & 63;
      const size_t src = (size_t)((b * 256 + pxg * 16 + nt) * 8 + s) * 64 + r;
      const short8 v1 = T1[src], v2 = T2[src];
      const float2 f = ff[nt * 16 + (r & 15)];
      short8 mg;
      #pragma unroll
      for (int j = 0; j < 8; ++j)
        mg[j] = f2bf(f.x * bf2f(v1[j]) + f.y * bf2f(v2[j]));
      tBs[idx] = mg;
    }
    __syncthreads();
    const short8 a = Av[((it * 8 + s) * 4 + qf) * 16 + m];
    #pragma unroll
    for (int nt = 0; nt < 16; ++nt)
      acc[nt] = __builtin_amdgcn_mfma_f32_16x16x32_bf16(a, tBs[nt * 64 + lane], acc[nt], 0, 0, 0);
  }
  // D layout: col = m (px), row = qf*4 + r (i)
  float* ob = out + (size_t)(b * 256) * 4096 + pxg * 256;
  #pragma unroll
  for (int nt = 0; nt < 16; ++nt)
    #pragma unroll
    for (int r = 0; r < 4; ++r) {
      const int i = it * 16 + qf * 4 + r;
      ob[(size_t)i * 4096 + nt * 16 + m] = acc[nt][r] + bo[i];
    }
}

extern "C" void kernel_launch(void* const* d_in, const int* in_sizes, int n_in,
                              void* d_out, int out_size, void* d_ws, size_t ws_size,
                              hipStream_t stream) {
  const float* q   = (const float*)d_in[0];
  const float* c   = (const float*)d_in[1];
  const float* g   = (const float*)d_in[2];
  const float* Wq  = (const float*)d_in[3];
  const float* Wkv = (const float*)d_in[4];
  const float* Wo  = (const float*)d_in[5];
  const float* bo  = (const float*)d_in[6];
  float* out = (float*)d_out;
  unsigned char* ws = (unsigned char*)d_ws;   // needs 17,174,528 bytes
  pre_kernel<<<68, 256, 0, stream>>>(q, g, Wq, Wkv, Wo, ws);
  attn_kernel<<<1024, 256, 0, stream>>>(c, ws, ws);
  gemm_kernel<<<256, 256, 0, stream>>>(bo, ws, out);
}

// Round 8
// 247.700 us; speedup vs baseline: 1.2069x; 1.0808x over previous
//
#include <hip/hip_runtime.h>

// B=4, N=8, C=256, H=64, W=64, D=512 (single query per batch).
// Algebraic collapse: c is read exactly once; K and V never formed.
//   gqk[b,c]  = g[c] * D^-0.5 * (Wkv_upper^T (Wq q_b))[c]
//   dots[n]   = inv_rms[n,px] * <c[b,n,:,px], gqk[b,:]>
//   t[c,px]   = sum_n softmax_n * inv_rms * c[b,n,c,px]
//   out       = Wovg @ t + bo,  Wovg = Wo @ Wkv_lower * diag(g)  (bf16 MFMA)
//
// R10 = revert to R7 (best measured: 249.1 us). Session ledger (R2-R9)
// falsified every candidate lever on the strided c-read rate (~2.4 TB/s):
// span size 128B-4KB (R7/R5: no change), fully-sequential streaming (R6:
// <=3.5 TB/s), 2-pass contiguous restructures (R4-R6: 276-284, worse),
// occupancy 2->4 waves/SIMD + half serial depth (R9: no change). Compiler
// rule (seen R3, R8): __launch_bounds__(_,4) => 64-VGPR squeeze + ~100 MB
// scratch spill; use (_,2). Floor arithmetic: ~187 us invariant harness
// overhead (2x 512 MiB timed poison fills @77 + gaps) + attn 147 MB @
// ~2.5 TB/s strided wall ~58-62 + pre ~4 = ~249 us. This kernel sits on it.
//
// Structure: block = (b,h) full 64-px row, 512 thr = 8 waves, 256 blocks.
// Thread = 8 ch x 4 px (t[8][4]+vals[8] ~110 VGPR, no spill under (512,2)).
// One barrier per token (double-buffered LDS partials); phase-3 bf16 MFMA
// from LDS B-fragments against A-fragment-linear Wovg.

typedef __attribute__((ext_vector_type(8))) short short8;
typedef __attribute__((ext_vector_type(4))) float floatx4;

static __device__ __forceinline__ short f2bf(float f) {
  unsigned u = __float_as_uint(f);
  u += 0x7fffu + ((u >> 16) & 1u);   // round-to-nearest-even
  return (short)(u >> 16);
}

// ws: [0,131072) WovgB bf16, A-fragment-linear: element (i,c) at short index
//     ((((i>>4)*8 + (c>>5))*4 + ((c>>3)&3))*16 + (i&15))*8 + (c&7)
//     [131072,135168) gqk f32 [4][256]
// blocks 0..63: Wovg rows 4i..4i+3; blocks 64..67: gqk for batch b
__global__ __launch_bounds__(256) void pre_kernel(
    const float* __restrict__ q, const float* __restrict__ g,
    const float* __restrict__ Wq, const float* __restrict__ Wkv,
    const float* __restrict__ Wo, unsigned char* __restrict__ ws) {
  short* WovgB = (short*)ws;
  float* gqk = (float*)(ws + 131072);
  const int blk = blockIdx.x, tid = threadIdx.x;
  if (blk < 64) {
    const int i0 = blk * 4, c = tid;
    float s0 = 0.f, s1 = 0.f, s2 = 0.f, s3 = 0.f;
    #pragma unroll 8
    for (int d = 0; d < 512; ++d) {
      const float wv = Wkv[(512 + d) * 256 + c];   // vector load
      s0 = fmaf(Wo[(i0 + 0) * 512 + d], wv, s0);   // Wo: uniform -> s_load
      s1 = fmaf(Wo[(i0 + 1) * 512 + d], wv, s1);
      s2 = fmaf(Wo[(i0 + 2) * 512 + d], wv, s2);
      s3 = fmaf(Wo[(i0 + 3) * 512 + d], wv, s3);
    }
    const float gc = g[c];
    const int sg = c >> 5, q2 = (c >> 3) & 3, jj = c & 7;
    const float sv[4] = {s0, s1, s2, s3};
    #pragma unroll
    for (int ii = 0; ii < 4; ++ii) {
      const int i = i0 + ii, it = i >> 4, m = i & 15;
      WovgB[((((it * 8 + sg) * 4 + q2) * 16) + m) * 8 + jj] = f2bf(sv[ii] * gc);
    }
  } else if (blk < 68) {
    const int b = blk - 64;
    __shared__ float qps[512];
    for (int d = tid; d < 512; d += 256) {
      float s = 0.f;
      #pragma unroll 16
      for (int cc = 0; cc < 256; ++cc)
        s = fmaf(Wq[d * 256 + cc], q[b * 256 + cc], s);
      qps[d] = s;
    }
    __syncthreads();
    const int c = tid;
    float s = 0.f;
    #pragma unroll 16
    for (int d = 0; d < 512; ++d)
      s = fmaf(Wkv[d * 256 + c], qps[d], s);
    gqk[b * 256 + c] = s * g[c] * 0.044194173824159216f;  // 512^-0.5
  }
}

// Block = (b, h): full 64-px row, 512 thr = 8 waves, 256 blocks (1/CU).
// Thread: cgrp = tid>>4 owns ch [cgrp*8, cgrp*8+8); pgrp = tid&15 owns
// px [pgrp*4, pgrp*4+4) via float4 -> 16 consecutive lanes = 256 B span.
__global__ __launch_bounds__(512, 2) void attn_kernel(
    const float* __restrict__ cin, const float* __restrict__ bo,
    const unsigned char* __restrict__ ws, float* __restrict__ out) {
  const short8* Av = (const short8*)ws;
  const float* gqk = (const float*)(ws + 131072);
  const int blk = blockIdx.x;                 // 256 blocks = b*64 + h
  const int b = blk >> 6, h = blk & 63;
  const int tid = threadIdx.x;
  const int lane = tid & 63, w = tid >> 6;    // w in 0..7
  const int cgrp = tid >> 4;                  // 0..31
  const int pgrp = tid & 15;                  // px0 = pgrp*4

  __shared__ short tB[8][4][64][8];           // 32 KB, B-fragment-linear
  __shared__ float redS[2][8][16][4], redD[2][8][16][4];   // 8 KB

  float rg[8];
  #pragma unroll
  for (int j = 0; j < 8; ++j) rg[j] = gqk[b * 256 + cgrp * 8 + j];

  float t[8][4];
  #pragma unroll
  for (int j = 0; j < 8; ++j)
    #pragma unroll
    for (int p = 0; p < 4; ++p) t[j][p] = 0.f;
  float mM[4], zZ[4];
  #pragma unroll
  for (int p = 0; p < 4; ++p) { mM[p] = -1e30f; zZ[p] = 0.f; }

  const float* cb = cin + ((size_t)(b * 8) * 256 + cgrp * 8) * 4096
                        + h * 64 + pgrp * 4;
  for (int n = 0; n < 8; ++n) {
    const float* cp = cb + (size_t)n * 256 * 4096;
    floatx4 vals[8];
    #pragma unroll
    for (int j = 0; j < 8; ++j)
      vals[j] = *(const floatx4*)(cp + (size_t)j * 4096);
    float ssq[4] = {0.f, 0.f, 0.f, 0.f}, dt[4] = {0.f, 0.f, 0.f, 0.f};
    #pragma unroll
    for (int j = 0; j < 8; ++j)
      #pragma unroll
      for (int p = 0; p < 4; ++p) {
        ssq[p] = fmaf(vals[j][p], vals[j][p], ssq[p]);
        dt[p] = fmaf(vals[j][p], rg[j], dt[p]);
      }
    // combine the wave's 4 cgrp sub-groups (lane bits 4,5)
    #pragma unroll
    for (int p = 0; p < 4; ++p) {
      ssq[p] += __shfl_xor(ssq[p], 16);
      ssq[p] += __shfl_xor(ssq[p], 32);
      dt[p] += __shfl_xor(dt[p], 16);
      dt[p] += __shfl_xor(dt[p], 32);
    }
    if ((lane >> 4) == 0) {
      #pragma unroll
      for (int p = 0; p < 4; ++p) {
        redS[n & 1][w][pgrp][p] = ssq[p];
        redD[n & 1][w][pgrp][p] = dt[p];
      }
    }
    __syncthreads();                          // the only barrier per token
    floatx4 S = {0.f, 0.f, 0.f, 0.f}, Dt = {0.f, 0.f, 0.f, 0.f};
    #pragma unroll
    for (int ww = 0; ww < 8; ++ww) {
      S += *(const floatx4*)(&redS[n & 1][ww][pgrp][0]);
      Dt += *(const floatx4*)(&redD[n & 1][ww][pgrp][0]);
    }
    float wn[4], al[4];
    #pragma unroll
    for (int p = 0; p < 4; ++p) {
      const float invr = rsqrtf(S[p] * (1.f / 256.f) + 1e-6f);
      const float d = Dt[p] * invr;
      const float mn = fmaxf(mM[p], d);
      al[p] = __expf(mM[p] - mn);             // 0 on first token
      const float e = __expf(d - mn);
      zZ[p] = zZ[p] * al[p] + e;
      mM[p] = mn;
      wn[p] = e * invr;
    }
    #pragma unroll
    for (int j = 0; j < 8; ++j)
      #pragma unroll
      for (int p = 0; p < 4; ++p)
        t[j][p] = fmaf(wn[p], vals[j][p], t[j][p] * al[p]);
  }

  // write normalized t (bf16) in B-fragment order:
  // reader lane L=(q*16+m) of (s,nt) wants ch=s*32+q*8+jj, px=nt*16+m.
  // writer: ch = cgrp*8+j -> s = cgrp>>2, q = cgrp&3; px = pgrp*4+p ->
  // nt = pgrp>>2, m = (pgrp&3)*4+p. Thread owns all 8 jj -> short8 stores.
  {
    const int s = cgrp >> 2, qq = cgrp & 3;
    const int nt = pgrp >> 2, mb = (pgrp & 3) * 4;
    #pragma unroll
    for (int p = 0; p < 4; ++p) {
      const float invZ = 1.f / zZ[p];
      short8 pk;
      #pragma unroll
      for (int j = 0; j < 8; ++j) pk[j] = f2bf(t[j][p] * invZ);
      *(short8*)(&tB[s][nt][qq * 16 + mb + p][0]) = pk;
    }
  }
  __syncthreads();

  // phase 3: out[256 i][64 px] = Wovg(bf16) @ t(bf16); wave w -> 32 i-rows
  const int qf = lane >> 4, m = lane & 15;
  floatx4 acc[2][4];
  #pragma unroll
  for (int mt = 0; mt < 2; ++mt)
    #pragma unroll
    for (int nt = 0; nt < 4; ++nt) acc[mt][nt] = (floatx4){0.f, 0.f, 0.f, 0.f};
  #pragma unroll
  for (int s = 0; s < 8; ++s) {
    short8 a[2];
    #pragma unroll
    for (int mt = 0; mt < 2; ++mt)            // coalesced: 16 B/lane
      a[mt] = Av[(((w * 2 + mt) * 8 + s) * 4 + qf) * 16 + m];
    #pragma unroll
    for (int nt = 0; nt < 4; ++nt) {
      const short8 bf = *(const short8*)(&tB[s][nt][lane][0]);
      #pragma unroll
      for (int mt = 0; mt < 2; ++mt)
        acc[mt][nt] = __builtin_amdgcn_mfma_f32_16x16x32_bf16(a[mt], bf, acc[mt][nt], 0, 0, 0);
    }
  }
  // epilogue: D layout col=lane&15(px), row=qf*4+r(i)
  float* ob = out + (size_t)b * 256 * 4096 + h * 64;
  #pragma unroll
  for (int mt = 0; mt < 2; ++mt) {
    float bov[4];
    #pragma unroll
    for (int r = 0; r < 4; ++r) bov[r] = bo[(w * 2 + mt) * 16 + qf * 4 + r];
    #pragma unroll
    for (int nt = 0; nt < 4; ++nt)
      #pragma unroll
      for (int r = 0; r < 4; ++r) {
        const int i = (w * 2 + mt) * 16 + qf * 4 + r;
        ob[(size_t)i * 4096 + nt * 16 + m] = acc[mt][nt][r] + bov[r];
      }
  }
}

extern "C" void kernel_launch(void* const* d_in, const int* in_sizes, int n_in,
                              void* d_out, int out_size, void* d_ws, size_t ws_size,
                              hipStream_t stream) {
  const float* q   = (const float*)d_in[0];
  const float* c   = (const float*)d_in[1];
  const float* g   = (const float*)d_in[2];
  const float* Wq  = (const float*)d_in[3];
  const float* Wkv = (const float*)d_in[4];
  const float* Wo  = (const float*)d_in[5];
  const float* bo  = (const float*)d_in[6];
  float* out = (float*)d_out;
  unsigned char* ws = (unsigned char*)d_ws;   // needs 135168 bytes
  pre_kernel<<<68, 256, 0, stream>>>(q, g, Wq, Wkv, Wo, ws);
  attn_kernel<<<256, 512, 0, stream>>>(c, bo, ws, out);
}